// Round 1
// baseline (248.400 us; speedup 1.0000x reference)
//
#include <hip/hip_runtime.h>

// CrossCompressUnit: rank-1 cross projections.
//   v_out = v * (e.w_vv) + e * (v.w_ev) + b_v
//   e_out = v * (e.w_ve) + e * (v.w_ee) + b_e
// B = 131072 rows, D = 128. Pure streaming, memory-bound.
//
// Layout: one 32-lane half-wave per row; each lane owns 4 contiguous floats
// (float4 = 16 B/lane, coalescing sweet spot). Dot products reduced via
// 5-step __shfl_xor butterfly within each 32-lane group (masks 1..16 never
// cross the 32-lane boundary, so the two rows sharing a wave64 reduce
// independently).

#define CCU_D 128

__global__ __launch_bounds__(256) void ccu_kernel(
    const float* __restrict__ v,
    const float* __restrict__ e,
    const float* __restrict__ w_vv,
    const float* __restrict__ w_ev,
    const float* __restrict__ w_ve,
    const float* __restrict__ w_ee,
    const float* __restrict__ b_v,
    const float* __restrict__ b_e,
    float* __restrict__ v_out,
    float* __restrict__ e_out,
    int nrows)
{
    const int lane32 = threadIdx.x & 31;            // column group within row
    int row = (int)((blockIdx.x * (size_t)blockDim.x + threadIdx.x) >> 5);
    const int row_stride = (int)((gridDim.x * (size_t)blockDim.x) >> 5);

    // Weights/biases: 128 floats each -> one float4 per lane32, loaded once.
    const float4 wvv = ((const float4*)w_vv)[lane32];
    const float4 wev = ((const float4*)w_ev)[lane32];
    const float4 wve = ((const float4*)w_ve)[lane32];
    const float4 wee = ((const float4*)w_ee)[lane32];
    const float4 bv  = ((const float4*)b_v )[lane32];
    const float4 be  = ((const float4*)b_e )[lane32];

    for (; row < nrows; row += row_stride) {
        const float4 vr = ((const float4*)(v + (size_t)row * CCU_D))[lane32];
        const float4 er = ((const float4*)(e + (size_t)row * CCU_D))[lane32];

        // Per-lane partial dot products (4 elements each).
        float d_evv = er.x * wvv.x + er.y * wvv.y + er.z * wvv.z + er.w * wvv.w;
        float d_vev = vr.x * wev.x + vr.y * wev.y + vr.z * wev.z + vr.w * wev.w;
        float d_eve = er.x * wve.x + er.y * wve.y + er.z * wve.z + er.w * wve.w;
        float d_vee = vr.x * wee.x + vr.y * wee.y + vr.z * wee.z + vr.w * wee.w;

        // Butterfly reduce across the 32 lanes of this row.
        #pragma unroll
        for (int off = 16; off >= 1; off >>= 1) {
            d_evv += __shfl_xor(d_evv, off);
            d_vev += __shfl_xor(d_vev, off);
            d_eve += __shfl_xor(d_eve, off);
            d_vee += __shfl_xor(d_vee, off);
        }

        float4 vo, eo;
        vo.x = vr.x * d_evv + er.x * d_vev + bv.x;
        vo.y = vr.y * d_evv + er.y * d_vev + bv.y;
        vo.z = vr.z * d_evv + er.z * d_vev + bv.z;
        vo.w = vr.w * d_evv + er.w * d_vev + bv.w;

        eo.x = vr.x * d_eve + er.x * d_vee + be.x;
        eo.y = vr.y * d_eve + er.y * d_vee + be.y;
        eo.z = vr.z * d_eve + er.z * d_vee + be.z;
        eo.w = vr.w * d_eve + er.w * d_vee + be.w;

        ((float4*)(v_out + (size_t)row * CCU_D))[lane32] = vo;
        ((float4*)(e_out + (size_t)row * CCU_D))[lane32] = eo;
    }
}

extern "C" void kernel_launch(void* const* d_in, const int* in_sizes, int n_in,
                              void* d_out, int out_size, void* d_ws, size_t ws_size,
                              hipStream_t stream) {
    const float* v    = (const float*)d_in[0];
    const float* e    = (const float*)d_in[1];
    const float* w_vv = (const float*)d_in[2];
    const float* w_ev = (const float*)d_in[3];
    const float* w_ve = (const float*)d_in[4];
    const float* w_ee = (const float*)d_in[5];
    const float* b_v  = (const float*)d_in[6];
    const float* b_e  = (const float*)d_in[7];

    const int nrows = in_sizes[0] / CCU_D;          // 131072
    float* v_out = (float*)d_out;                   // [nrows * D]
    float* e_out = (float*)d_out + (size_t)nrows * CCU_D;

    // 8 rows per 256-thread block; grid-stride. 2048 blocks = 8 blocks/CU.
    const int blocks = 2048;
    ccu_kernel<<<blocks, 256, 0, stream>>>(v, e, w_vv, w_ev, w_ve, w_ee,
                                           b_v, b_e, v_out, e_out, nrows);
}

// Round 2
// 246.508 us; speedup vs baseline: 1.0077x; 1.0077x over previous
//
#include <hip/hip_runtime.h>

// CrossCompressUnit: rank-1 cross projections.
//   v_out = v * (e.w_vv) + e * (v.w_ev) + b_v
//   e_out = v * (e.w_ve) + e * (v.w_ee) + b_e
// B = 131072 rows, D = 128, f32. Memory-bound (ideal ~268 MB total -> ~43 us).
//
// Round 2: latency-bound fix. Each 32-lane group owns 4 CONSECUTIVE rows and
// issues all 8 float4 loads up front (8 KiB in flight per wave vs 2 KiB in
// round 1), then runs 16 independent butterfly-reduce chains interleaved.
// Grid exactly covers B (no grid-stride loop -> no loop-carried serial chain).

#define CCU_D 128
#define ROWS_PER_GROUP 4

__device__ __forceinline__ float dot4(const float4 a, const float4 b) {
    return a.x * b.x + a.y * b.y + a.z * b.z + a.w * b.w;
}

__global__ __launch_bounds__(256) void ccu_kernel(
    const float* __restrict__ v,
    const float* __restrict__ e,
    const float* __restrict__ w_vv,
    const float* __restrict__ w_ev,
    const float* __restrict__ w_ve,
    const float* __restrict__ w_ee,
    const float* __restrict__ b_v,
    const float* __restrict__ b_e,
    float* __restrict__ v_out,
    float* __restrict__ e_out,
    int nrows)
{
    const int lane32 = threadIdx.x & 31;   // column group within row (16B each)
    const int group  = (int)((blockIdx.x * (size_t)blockDim.x + threadIdx.x) >> 5);
    const int base   = group * ROWS_PER_GROUP;   // first of 4 consecutive rows
    if (base >= nrows) return;

    // Weights/biases: 128 floats each -> one float4 per lane32 (L1/L2-hot).
    const float4 wvv = ((const float4*)w_vv)[lane32];
    const float4 wev = ((const float4*)w_ev)[lane32];
    const float4 wve = ((const float4*)w_ve)[lane32];
    const float4 wee = ((const float4*)w_ee)[lane32];

    // Issue ALL loads first: 8 outstanding global_load_dwordx4 per thread.
    float4 vr[ROWS_PER_GROUP], er[ROWS_PER_GROUP];
    #pragma unroll
    for (int k = 0; k < ROWS_PER_GROUP; ++k) {
        vr[k] = ((const float4*)(v + (size_t)(base + k) * CCU_D))[lane32];
        er[k] = ((const float4*)(e + (size_t)(base + k) * CCU_D))[lane32];
    }

    // Per-lane partial dot products: 16 independent values.
    float dvv[ROWS_PER_GROUP], dev[ROWS_PER_GROUP];
    float dve[ROWS_PER_GROUP], dee[ROWS_PER_GROUP];
    #pragma unroll
    for (int k = 0; k < ROWS_PER_GROUP; ++k) {
        dvv[k] = dot4(er[k], wvv);
        dev[k] = dot4(vr[k], wev);
        dve[k] = dot4(er[k], wve);
        dee[k] = dot4(vr[k], wee);
    }

    // Butterfly reduce across the 32 lanes of each row; 16 chains interleave,
    // so the per-step ds_swizzle latency is hidden across chains.
    #pragma unroll
    for (int off = 16; off >= 1; off >>= 1) {
        #pragma unroll
        for (int k = 0; k < ROWS_PER_GROUP; ++k) {
            dvv[k] += __shfl_xor(dvv[k], off);
            dev[k] += __shfl_xor(dev[k], off);
            dve[k] += __shfl_xor(dve[k], off);
            dee[k] += __shfl_xor(dee[k], off);
        }
    }

    const float4 bv = ((const float4*)b_v)[lane32];
    const float4 be = ((const float4*)b_e)[lane32];

    #pragma unroll
    for (int k = 0; k < ROWS_PER_GROUP; ++k) {
        float4 vo, eo;
        vo.x = vr[k].x * dvv[k] + er[k].x * dev[k] + bv.x;
        vo.y = vr[k].y * dvv[k] + er[k].y * dev[k] + bv.y;
        vo.z = vr[k].z * dvv[k] + er[k].z * dev[k] + bv.z;
        vo.w = vr[k].w * dvv[k] + er[k].w * dev[k] + bv.w;

        eo.x = vr[k].x * dve[k] + er[k].x * dee[k] + be.x;
        eo.y = vr[k].y * dve[k] + er[k].y * dee[k] + be.y;
        eo.z = vr[k].z * dve[k] + er[k].z * dee[k] + be.z;
        eo.w = vr[k].w * dve[k] + er[k].w * dee[k] + be.w;

        ((float4*)(v_out + (size_t)(base + k) * CCU_D))[lane32] = vo;
        ((float4*)(e_out + (size_t)(base + k) * CCU_D))[lane32] = eo;
    }
}

extern "C" void kernel_launch(void* const* d_in, const int* in_sizes, int n_in,
                              void* d_out, int out_size, void* d_ws, size_t ws_size,
                              hipStream_t stream) {
    const float* v    = (const float*)d_in[0];
    const float* e    = (const float*)d_in[1];
    const float* w_vv = (const float*)d_in[2];
    const float* w_ev = (const float*)d_in[3];
    const float* w_ve = (const float*)d_in[4];
    const float* w_ee = (const float*)d_in[5];
    const float* b_v  = (const float*)d_in[6];
    const float* b_e  = (const float*)d_in[7];

    const int nrows = in_sizes[0] / CCU_D;          // 131072
    float* v_out = (float*)d_out;                   // [nrows * D]
    float* e_out = (float*)d_out + (size_t)nrows * CCU_D;

    // 8 groups/block * 4 rows/group = 32 rows per 256-thread block.
    const int rows_per_block = (256 / 32) * ROWS_PER_GROUP;
    const int blocks = (nrows + rows_per_block - 1) / rows_per_block;  // 4096
    ccu_kernel<<<blocks, 256, 0, stream>>>(v, e, w_vv, w_ev, w_ve, w_ee,
                                           b_v, b_e, v_out, e_out, nrows);
}